// Round 5
// baseline (184.622 us; speedup 1.0000x reference)
//
#include <hip/hip_runtime.h>
#include <stdint.h>

// HybridSymmetricLoss: B=65536, T=3, J=10 (fp32).
// C[tl][ta] = sum_jk BCE(assign[b,ta,jk], labels[b,tl,jk]);
// loss = min over 6 perms of mean C[t][perm[t]] + category BCE under the
// argmin perm.  Logs in log2 space (clip -100/ln2), one ln2 scale at end.
//
// R5 structure: decouple streaming from compute.
//  - Tile = 8 b's.  A-tile and Y-tile (9600 B each) staged into LDS with
//    async global_load_lds width=16 (wave-uniform dest + lane*16; fully
//    contiguous, 1 KB per wave-instr) — no VGPR round-trip, loads stay in
//    flight across the whole compute phase (fixes R2-R4 latency wall).
//  - Double-buffered: 38.4 KB LDS/block -> 4 blocks/CU, 16 waves/CU.
//  - Compute: 32 lanes per b; lane j<25 owns jk4 chunk j (ds_read_b128 x6);
//    9 partials (s1 folded), 5-stage intra-32 butterfly; epilogue on j==0.
//  - Two-pass final sum via d_ws.

#define CLIP2 (-144.26950408889634f)   // -100 / ln(2)
#define LN2   (0.6931471805599453f)

#define TILE_B     8
#define TILE_F     (TILE_B * 300)      // 2400 floats per array per tile
#define TILE_BYTES (TILE_F * 4)        // 9600 B
#define NCHUNK     10                  // ceil(9600 / 1024); last chunk 384 B

__device__ __forceinline__ void stage_tile(const float* __restrict__ gA,
                                           const float* __restrict__ gY,
                                           float* lA, float* lY,
                                           int wave, int lane) {
    for (int c = wave; c < NCHUNK; c += 4) {
        const int off = c * 1024 + lane * 16;          // byte offset
        if (off < TILE_BYTES) {
            __builtin_amdgcn_global_load_lds(
                (const __attribute__((address_space(1))) uint32_t*)((const char*)gA + off),
                (__attribute__((address_space(3))) uint32_t*)((char*)lA + c * 1024),
                16, 0, 0);
            __builtin_amdgcn_global_load_lds(
                (const __attribute__((address_space(1))) uint32_t*)((const char*)gY + off),
                (__attribute__((address_space(3))) uint32_t*)((char*)lY + c * 1024),
                16, 0, 0);
        }
    }
}

__launch_bounds__(256, 4)
__global__ void hybrid_pass1(const float* __restrict__ assign,
                             const float* __restrict__ cat,
                             const float* __restrict__ assign_lab,
                             const float* __restrict__ cat_lab,
                             float* __restrict__ ws, int B) {
    __shared__ alignas(16) float lds[2][2][TILE_F];    // [buf][A/Y][floats]

    const int lane = threadIdx.x & 63;
    const int wave = threadIdx.x >> 6;
    const int g    = threadIdx.x >> 5;                 // b within tile (0..7)
    const int j    = threadIdx.x & 31;                 // lane within b-group
    const bool act = j < 25;                           // 25 jk4 chunks

    const int ntiles = B / TILE_B;                     // B % 8 == 0
    float lsum = 0.f;

    int t = blockIdx.x;
    if (t < ntiles)
        stage_tile(assign + (size_t)t * TILE_F, assign_lab + (size_t)t * TILE_F,
                   lds[0][0], lds[0][1], wave, lane);

    int buf = 0;
    for (; t < ntiles; t += gridDim.x) {
        __builtin_amdgcn_s_waitcnt(0x0f70);            // vmcnt(0) only
        __syncthreads();                               // tile t staged; prev compute done

        const int tn = t + gridDim.x;
        if (tn < ntiles)
            stage_tile(assign + (size_t)tn * TILE_F,
                       assign_lab + (size_t)tn * TILE_F,
                       lds[buf ^ 1][0], lds[buf ^ 1][1], wave, lane);

        // ---- compute tile t from lds[buf] ----
        const int b = t * TILE_B + g;

        // category prefetch early (only j==0 consumes it)
        float cb0=0.f,cb1=0.f,cb2=0.f,gb0=0.f,gb1=0.f,gb2=0.f;
        if (j == 0) {
            const float* cp = cat     + (size_t)b * 3;
            const float* gp = cat_lab + (size_t)b * 3;
            cb0 = cp[0]; cb1 = cp[1]; cb2 = cp[2];
            gb0 = gp[0]; gb1 = gp[1]; gb2 = gp[2];
        }

        float e[3][3] = {{0.f,0.f,0.f},{0.f,0.f,0.f},{0.f,0.f,0.f}};
        if (act) {
            const int f = g * 300 + j * 4;
            float4 av[3], yv[3];
            #pragma unroll
            for (int tt = 0; tt < 3; ++tt) {
                av[tt] = *(const float4*)&lds[buf][0][f + tt * 100];
                yv[tt] = *(const float4*)&lds[buf][1][f + tt * 100];
            }
            float d[3][4];
            float s1a[3] = {0.f, 0.f, 0.f};
            #pragma unroll
            for (int tt = 0; tt < 3; ++tt) {
                float a[4] = {av[tt].x, av[tt].y, av[tt].z, av[tt].w};
                #pragma unroll
                for (int c = 0; c < 4; ++c) {
                    float lp = fmaxf(__log2f(a[c]),        CLIP2);
                    float l1 = fmaxf(__log2f(1.0f - a[c]), CLIP2);
                    d[tt][c] = lp - l1;
                    s1a[tt] += l1;
                }
            }
            #pragma unroll
            for (int tl = 0; tl < 3; ++tl) {
                float y[4] = {yv[tl].x, yv[tl].y, yv[tl].z, yv[tl].w};
                #pragma unroll
                for (int ta = 0; ta < 3; ++ta) {
                    float acc = s1a[ta];
                    #pragma unroll
                    for (int c = 0; c < 4; ++c)
                        acc = fmaf(y[c], d[ta][c], acc);
                    e[tl][ta] = acc;
                }
            }
        }

        // 5-stage butterfly within each 32-lane group
        #pragma unroll
        for (int off = 1; off <= 16; off <<= 1)
            #pragma unroll
            for (int tl = 0; tl < 3; ++tl)
                #pragma unroll
                for (int ta = 0; ta < 3; ++ta)
                    e[tl][ta] += __shfl_xor(e[tl][ta], off, 64);

        if (j == 0) {
            // min over perms of C = -ln2*e  ==  max over perms of e
            const int P0[6] = {0,0,1,1,2,2};
            const int P1[6] = {1,2,0,2,0,1};
            const int P2[6] = {2,1,2,0,1,0};
            float best = e[0][0] + e[1][1] + e[2][2];
            int bp0 = 0, bp1 = 1, bp2 = 2;
            #pragma unroll
            for (int p = 1; p < 6; ++p) {
                float l = e[0][P0[p]] + e[1][P1[p]] + e[2][P2[p]];
                if (l > best) { best = l; bp0 = P0[p]; bp1 = P1[p]; bp2 = P2[p]; }
            }

            float lp0 = fmaxf(__log2f(cb0), CLIP2), l10 = fmaxf(__log2f(1.f-cb0), CLIP2);
            float lp1 = fmaxf(__log2f(cb1), CLIP2), l11 = fmaxf(__log2f(1.f-cb1), CLIP2);
            float lp2 = fmaxf(__log2f(cb2), CLIP2), l12 = fmaxf(__log2f(1.f-cb2), CLIP2);

            float lpa = (bp0==0)?lp0:((bp0==1)?lp1:lp2);
            float l1a = (bp0==0)?l10:((bp0==1)?l11:l12);
            float lpb = (bp1==0)?lp0:((bp1==1)?lp1:lp2);
            float l1b = (bp1==0)?l10:((bp1==1)?l11:l12);
            float lpc = (bp2==0)?lp0:((bp2==1)?lp1:lp2);
            float l1c = (bp2==0)?l10:((bp2==1)?l11:l12);

            float csum = -(gb0*lpa + (1.f-gb0)*l1a
                         + gb1*lpb + (1.f-gb1)*l1b
                         + gb2*lpc + (1.f-gb2)*l1c);

            lsum += best * (-1.f/300.f) + csum * (1.f/3.f);
        }
        buf ^= 1;
    }

    // block reduce: lsum nonzero on j==0 lanes (lane 0 and 32 of each wave)
    lsum += __shfl_xor(lsum, 32, 64);
    __shared__ float sred[4];
    if (lane == 0) sred[wave] = lsum;
    __syncthreads();
    if (threadIdx.x == 0) {
        float s = (sred[0] + sred[1]) + (sred[2] + sred[3]);
        ws[blockIdx.x] = s * (LN2 / (float)B);
    }
}

__launch_bounds__(1024)
__global__ void hybrid_pass2(const float* __restrict__ ws,
                             float* __restrict__ out, int n) {
    float s = 0.f;
    for (int i = threadIdx.x; i < n; i += 1024) s += ws[i];
    #pragma unroll
    for (int off = 32; off > 0; off >>= 1) s += __shfl_xor(s, off, 64);
    __shared__ float sm[16];
    if ((threadIdx.x & 63) == 0) sm[threadIdx.x >> 6] = s;
    __syncthreads();
    if (threadIdx.x == 0) {
        float t = 0.f;
        #pragma unroll
        for (int i = 0; i < 16; ++i) t += sm[i];
        out[0] = t;
    }
}

extern "C" void kernel_launch(void* const* d_in, const int* in_sizes, int n_in,
                              void* d_out, int out_size, void* d_ws, size_t ws_size,
                              hipStream_t stream) {
    const float* assign     = (const float*)d_in[0];
    const float* cat        = (const float*)d_in[1];
    const float* assign_lab = (const float*)d_in[2];
    const float* cat_lab    = (const float*)d_in[3];
    float* out = (float*)d_out;
    float* ws  = (float*)d_ws;

    const int B = in_sizes[0] / 300;               // T*J*J = 300; B % 8 == 0
    const int blocks = 1024;                       // 4 resident blocks/CU

    hybrid_pass1<<<blocks, 256, 0, stream>>>(assign, cat, assign_lab,
                                             cat_lab, ws, B);
    hybrid_pass2<<<1, 1024, 0, stream>>>(ws, out, blocks);
}

// Round 7
// 164.492 us; speedup vs baseline: 1.1224x; 1.1224x over previous
//
#include <hip/hip_runtime.h>

// HybridSymmetricLoss: B=65536, T=3, J=10 (fp32).
// C[tl][ta] = sum_jk BCE(assign[b,ta,jk], labels[b,tl,jk]);
// loss = min over 6 perms of mean C[t][perm[t]] + category BCE under the
// argmin perm.  Logs in log2 space (clip -100/ln2), one ln2 scale at end.
//
// R7 = R6 with the compile fix: __builtin_nontemporal_load requires a
// native clang vector type, not HIP's float4 struct.
// Carrier: R2 structure (one b per 32-lane half-wave, lanes 0..24 hold
// 4 jk via float4, 5-stage intra-half butterfly of 9 folded partials)
// + NON-TEMPORAL loads on the two 78.6 MB arrays.
// Two-pass final sum via d_ws.

#define CLIP2 (-144.26950408889634f)   // -100 / ln(2)
#define LN2   (0.6931471805599453f)

typedef float vfloat4 __attribute__((ext_vector_type(4)));

__launch_bounds__(256)
__global__ void hybrid_pass1(const float* __restrict__ assign,
                             const float* __restrict__ cat,
                             const float* __restrict__ assign_lab,
                             const float* __restrict__ cat_lab,
                             float* __restrict__ ws, int B) {
    const int sub = threadIdx.x & 31;               // lane within half-wave
    const int b   = (blockIdx.x * blockDim.x + threadIdx.x) >> 5;
    if (b >= B) return;

    const bool act = sub < 25;                      // 25 lanes * 4 = 100 jk
    float e[3][3] = {{0.f,0.f,0.f},{0.f,0.f,0.f},{0.f,0.f,0.f}};

    if (act) {
        const vfloat4* Ab = (const vfloat4*)(assign     + (size_t)b * 300 + sub * 4);
        const vfloat4* Yb = (const vfloat4*)(assign_lab + (size_t)b * 300 + sub * 4);
        vfloat4 av[3], yv[3];
        #pragma unroll
        for (int t = 0; t < 3; ++t) {
            av[t] = __builtin_nontemporal_load(Ab + t * 25);   // +100 floats
            yv[t] = __builtin_nontemporal_load(Yb + t * 25);
        }

        float d[3][4];
        float s1p[3] = {0.f, 0.f, 0.f};
        #pragma unroll
        for (int t = 0; t < 3; ++t) {
            #pragma unroll
            for (int c = 0; c < 4; ++c) {
                float a  = av[t][c];
                float lp = fmaxf(__log2f(a),        CLIP2);
                float l1 = fmaxf(__log2f(1.0f - a), CLIP2);
                d[t][c] = lp - l1;
                s1p[t] += l1;
            }
        }
        #pragma unroll
        for (int tl = 0; tl < 3; ++tl) {
            #pragma unroll
            for (int ta = 0; ta < 3; ++ta) {
                float acc = s1p[ta];
                #pragma unroll
                for (int c = 0; c < 4; ++c)
                    acc = fmaf(yv[tl][c], d[ta][c], acc);
                e[tl][ta] = acc;
            }
        }
    }

    // category prefetch so its latency overlaps the butterfly
    float cb0=0.f,cb1=0.f,cb2=0.f,gb0=0.f,gb1=0.f,gb2=0.f;
    if (sub == 0) {
        const float* cp = cat     + (size_t)b * 3;
        const float* gp = cat_lab + (size_t)b * 3;
        cb0 = cp[0]; cb1 = cp[1]; cb2 = cp[2];
        gb0 = gp[0]; gb1 = gp[1]; gb2 = gp[2];
    }

    // 5-stage butterfly within each 32-lane half (both halves in parallel)
    #pragma unroll
    for (int off = 1; off <= 16; off <<= 1)
        #pragma unroll
        for (int tl = 0; tl < 3; ++tl)
            #pragma unroll
            for (int ta = 0; ta < 3; ++ta)
                e[tl][ta] += __shfl_xor(e[tl][ta], off, 64);

    float lsum = 0.f;
    if (sub == 0) {
        // min over perms of C = -ln2*e  ==  max over perms of e
        const int P0[6] = {0,0,1,1,2,2};
        const int P1[6] = {1,2,0,2,0,1};
        const int P2[6] = {2,1,2,0,1,0};
        float best = e[0][0] + e[1][1] + e[2][2];
        int bp0 = 0, bp1 = 1, bp2 = 2;
        #pragma unroll
        for (int p = 1; p < 6; ++p) {
            float l = e[0][P0[p]] + e[1][P1[p]] + e[2][P2[p]];
            if (l > best) { best = l; bp0 = P0[p]; bp1 = P1[p]; bp2 = P2[p]; }
        }

        float lp0 = fmaxf(__log2f(cb0), CLIP2), l10 = fmaxf(__log2f(1.f-cb0), CLIP2);
        float lp1 = fmaxf(__log2f(cb1), CLIP2), l11 = fmaxf(__log2f(1.f-cb1), CLIP2);
        float lp2 = fmaxf(__log2f(cb2), CLIP2), l12 = fmaxf(__log2f(1.f-cb2), CLIP2);

        float lpa = (bp0==0)?lp0:((bp0==1)?lp1:lp2);
        float l1a = (bp0==0)?l10:((bp0==1)?l11:l12);
        float lpb = (bp1==0)?lp0:((bp1==1)?lp1:lp2);
        float l1b = (bp1==0)?l10:((bp1==1)?l11:l12);
        float lpc = (bp2==0)?lp0:((bp2==1)?lp1:lp2);
        float l1c = (bp2==0)?l10:((bp2==1)?l11:l12);

        float csum = -(gb0*lpa + (1.f-gb0)*l1a
                     + gb1*lpb + (1.f-gb1)*l1b
                     + gb2*lpc + (1.f-gb2)*l1c);

        lsum = best * (-1.f/300.f) + csum * (1.f/3.f);
    }

    // block reduce: 8 half-wave leaders per 256-thread block
    __shared__ float sred[8];
    if (sub == 0) sred[threadIdx.x >> 5] = lsum;
    __syncthreads();
    if (threadIdx.x == 0) {
        float s = 0.f;
        #pragma unroll
        for (int i = 0; i < 8; ++i) s += sred[i];
        ws[blockIdx.x] = s * (LN2 / (float)B);
    }
}

__launch_bounds__(1024)
__global__ void hybrid_pass2(const float* __restrict__ ws,
                             float* __restrict__ out, int n) {
    float s = 0.f;
    for (int i = threadIdx.x; i < n; i += 1024) s += ws[i];
    #pragma unroll
    for (int off = 32; off > 0; off >>= 1) s += __shfl_xor(s, off, 64);
    __shared__ float sm[16];
    if ((threadIdx.x & 63) == 0) sm[threadIdx.x >> 6] = s;
    __syncthreads();
    if (threadIdx.x == 0) {
        float t = 0.f;
        #pragma unroll
        for (int i = 0; i < 16; ++i) t += sm[i];
        out[0] = t;
    }
}

extern "C" void kernel_launch(void* const* d_in, const int* in_sizes, int n_in,
                              void* d_out, int out_size, void* d_ws, size_t ws_size,
                              hipStream_t stream) {
    const float* assign     = (const float*)d_in[0];
    const float* cat        = (const float*)d_in[1];
    const float* assign_lab = (const float*)d_in[2];
    const float* cat_lab    = (const float*)d_in[3];
    float* out = (float*)d_out;
    float* ws  = (float*)d_ws;

    const int B = in_sizes[0] / 300;               // T*J*J = 300
    const int blocks = (B * 32 + 255) / 256;       // one b per 32-lane half

    hybrid_pass1<<<blocks, 256, 0, stream>>>(assign, cat, assign_lab,
                                             cat_lab, ws, B);
    hybrid_pass2<<<1, 1024, 0, stream>>>(ws, out, blocks);
}